// Round 10
// baseline (421.863 us; speedup 1.0000x reference)
//
#include <hip/hip_runtime.h>
#include <hip/hip_cooperative_groups.h>
#include <math.h>

namespace cg = cooperative_groups;

#define B_N 8
#define IN_N 8
#define J_N 8
#define S_N 187
#define F_N 64
#define O_N 64
#define C_N 67
#define KS_N 15
#define SF_N (S_N * F_N)   // 11968
#define SF4_N (SF_N / 4)   // 2992 float4s per (b,i) plane
#define SQRT_SF 0.85467470f  // sqrt(187/256)

#define NT_SPL 12           // 1024-wide idx tiles (256 float4/block) covering SF_N
#define NCOMB 384           // combined+xp units (8 b * 4 jg * 12 tiles)
#define NKT16 768           // ktqt16 units (64 bj * 12 stiles)
#define NRF 768             // rawfinal units (64 bj * 12 stiles)
#define NMAXP 256           // maxabs partial blocks (fallback path)
#define NMEGA 768           // cooperative grid
#define FRAG_BJ 49152       // 12 stiles * 4096 halves per bj
#define W1STRIDE 196        // w1t row stride: 16B-aligned, bank-staggered
#define SMEM_F 8464         // LDS union (floats): comb_xp needs 8464 (33856 B)

typedef __attribute__((ext_vector_type(8))) _Float16 half8;
typedef __attribute__((ext_vector_type(4))) _Float16 half4;
typedef __attribute__((ext_vector_type(4))) float floatx4;

// ---------------- wave helpers (wave = 64) ----------------
__device__ __forceinline__ float wave_sum(float v) {
#pragma unroll
  for (int off = 32; off > 0; off >>= 1) v += __shfl_down(v, off, 64);
  return __shfl(v, 0, 64);
}
__device__ __forceinline__ float wave_max(float v) {
#pragma unroll
  for (int off = 32; off > 0; off >>= 1) v = fmaxf(v, __shfl_down(v, off, 64));
  return __shfl(v, 0, 64);
}
__device__ __forceinline__ float bspline(float d) {
  float t2 = fmaxf(2.f - d, 0.f);
  float t1 = fmaxf(1.f - d, 0.f);
  return t2 * t2 * t2 * (1.f / 6.f) - t1 * t1 * t1 * (4.f / 6.f);
}
// global |x| scale from n partial maxima (n = 256 fallback / 768 mega)
__device__ __forceinline__ float inv_from_partials(const float* __restrict__ maxp, int n) {
  int lane = threadIdx.x & 63;
  float m = 0.f;
  for (int k = lane; k < n; k += 64) m = fmaxf(m, maxp[k]);
  return 0.95f / (wave_max(m) + 1e-8f);
}
// gate = (sqrtE/tau) * sigmoid((sqrtE-tau)/tv) from the 12 per-tile partials
__device__ __forceinline__ float gate_g(const float* __restrict__ esum_p, int bi, int j,
                                        const float* __restrict__ tau, float tv) {
  const float* p = esum_p + ((long)bi * 8 + j) * NT_SPL;
  float s = 0.f;
#pragma unroll
  for (int k = 0; k < NT_SPL; k++) s += p[k];
  float sE = sqrtf(s * (1.f / (float)SF_N) + 1e-8f);
  float ta = fabsf(tau[(bi & 7) * 8 + j]);
  return (sE / (ta + 1e-8f)) / (1.f + expf(-(sE - ta) / tv));
}

// ================= phase bodies (shared by mega + fallback) =================

// ---- spline: act + energy partials for plane bi, tile ----
__device__ void spline_body(int tile, int bi, float inv, float* smem,
                            const float4* __restrict__ x4, const float* __restrict__ sw,
                            const float* __restrict__ omiga,
                            float4* __restrict__ act4, float* __restrict__ esum_p) {
  float* wl  = smem;            // [c][j] 536
  float* aom = smem + 536;      // 8
  float* red = smem + 544;      // 32
  int tid = threadIdx.x, lane = tid & 63, wid = tid >> 6;
  int i = bi & 7;
  __syncthreads();
  for (int t = tid; t < J_N * C_N; t += 256) {
    int j = t / C_N, c = t - j * C_N;
    wl[c * 8 + j] = sw[i * J_N * C_N + t];
  }
  if (tid < J_N) aom[tid] = fabsf(omiga[i * J_N + tid]);
  __syncthreads();
  int i4 = tile * 256 + tid;
  float e[J_N] = {0, 0, 0, 0, 0, 0, 0, 0};
  if (i4 < SF4_N) {
    float4 xv = x4[(long)bi * SF4_N + i4];
    float xs[4] = {xv.x, xv.y, xv.z, xv.w};
    float4 av[J_N];
#pragma unroll
    for (int c = 0; c < 4; c++) {
      float x = xs[c];
      float xn = fminf(fmaxf(x * inv, -0.99f), 0.99f);
      float u = (xn + 1.f) * 33.f;
      int c0 = (int)floorf(u) - 1;
      float sm[J_N] = {0, 0, 0, 0, 0, 0, 0, 0};
#pragma unroll
      for (int kk = 0; kk < 4; kk++) {
        int cc = c0 + kk;
        if (cc >= 0 && cc < C_N) {
          float bas = bspline(fabsf(u - (float)cc));
          const float4* wp = (const float4*)(wl + cc * 8);
          float4 wa = wp[0], wb = wp[1];
          sm[0] += bas * wa.x; sm[1] += bas * wa.y;
          sm[2] += bas * wa.z; sm[3] += bas * wa.w;
          sm[4] += bas * wb.x; sm[5] += bas * wb.y;
          sm[6] += bas * wb.z; sm[7] += bas * wb.w;
        }
      }
#pragma unroll
      for (int j = 0; j < J_N; j++) {
        float a = sm[j] + aom[j] * x;
        (&av[j].x)[c] = a;
        e[j] += a * a;
      }
    }
#pragma unroll
    for (int j = 0; j < J_N; j++) act4[((long)(bi * 8 + j)) * SF4_N + i4] = av[j];
  }
#pragma unroll
  for (int j = 0; j < J_N; j++) {
    float v = e[j];
#pragma unroll
    for (int off = 32; off > 0; off >>= 1) v += __shfl_down(v, off, 64);
    if (lane == 0) red[wid * J_N + j] = v;
  }
  __syncthreads();
  if (tid < J_N)
    esum_p[((long)bi * 8 + tid) * NT_SPL + tile] =
        red[tid] + red[8 + tid] + red[16 + tid] + red[24 + tid];
}

// ---- combined + fused xp for unit blk in [0, NCOMB) ----
__device__ void comb_xp_body(int blk, float* smem, const float4* __restrict__ act4,
                             const float* __restrict__ esum_p, const float* __restrict__ tau,
                             const float* __restrict__ temp, const float* __restrict__ W2,
                             const float* __restrict__ bparam, const float* __restrict__ lns,
                             const float* __restrict__ lnb, float4* __restrict__ comb4,
                             float* __restrict__ xprime) {
  int lane = threadIdx.x & 63;
  int tile = blk % 12, bjg = blk / 12;
  int jg = bjg & 3, b = bjg >> 2;
  int j0 = jg * 2;
  float* w2s = smem;             // [2][64][64]
  float* mk  = smem + 8192;      // 16
  float* lss = smem + 8208;      // [2][64]
  float* lbs = smem + 8336;      // [2][64]
  __syncthreads();
  {
    const float4* wg = (const float4*)(W2 + j0 * 4096);
    float4* ws4 = (float4*)w2s;
    for (int t = threadIdx.x; t < 2048; t += 256) ws4[t] = wg[t];
  }
  if (threadIdx.x < 128) {
    int jj = threadIdx.x >> 6, f = threadIdx.x & 63;
    lss[threadIdx.x] = lns[(j0 + jj) * 64 + f];
    lbs[threadIdx.x] = lnb[(j0 + jj) * 64 + f];
  }
  if (threadIdx.x < 16) {
    int i = threadIdx.x >> 1, j = j0 + (threadIdx.x & 1);
    const float* p = esum_p + ((long)(b * 8 + i) * 8 + j) * NT_SPL;
    float s = 0.f;
#pragma unroll
    for (int k = 0; k < NT_SPL; k++) s += p[k];
    float sE = sqrtf(s * (1.f / (float)SF_N) + 1e-8f);
    float ta = fabsf(tau[i * 8 + j]);
    float tv = fabsf(temp[0]) * SQRT_SF + 1e-4f;
    mk[threadIdx.x] = 1.f / (1.f + expf(-(sE - ta) / tv));
  }
  __syncthreads();
  int i4 = tile * 256 + threadIdx.x;
  if (i4 < SF4_N) {
    float4 cb[2] = {};
#pragma unroll
    for (int i = 0; i < IN_N; i++) {
#pragma unroll
      for (int jj = 0; jj < 2; jj++) {
        float4 a = act4[((long)((b * 8 + i) * 8 + j0 + jj)) * SF4_N + i4];
        float g = mk[i * 2 + jj];
        cb[jj].x += g * a.x; cb[jj].y += g * a.y;
        cb[jj].z += g * a.z; cb[jj].w += g * a.w;
      }
    }
#pragma unroll
    for (int jj = 0; jj < 2; jj++)
      comb4[((long)(b * J_N + j0 + jj)) * SF4_N + i4] = cb[jj];
    // ---- fused xp: LN over f (16-lane row) + W2 matmul + bparam ----
    int s = i4 >> 4;                       // global seq row (< S_N by guard)
    int fx = (threadIdx.x & 15) * 4;       // this lane's 4 o/h positions
    int g0 = lane & 48;                    // 16-lane group base within wave
#pragma unroll
    for (int jj = 0; jj < 2; jj++) {
      float4 c = cb[jj];
      float ls = c.x + c.y + c.z + c.w;
#pragma unroll
      for (int m = 1; m <= 8; m <<= 1) ls += __shfl_xor(ls, m, 64);
      float mean = ls * (1.f / 64.f);
      float d0 = c.x - mean, d1 = c.y - mean, d2 = c.z - mean, d3 = c.w - mean;
      float lv = d0 * d0 + d1 * d1 + d2 * d2 + d3 * d3;
#pragma unroll
      for (int m = 1; m <= 8; m <<= 1) lv += __shfl_xor(lv, m, 64);
      float invsd = 1.f / sqrtf(lv * (1.f / 64.f) + 1e-5f);
      float xln0 = d0 * invsd * lss[jj * 64 + fx + 0] + lbs[jj * 64 + fx + 0];
      float xln1 = d1 * invsd * lss[jj * 64 + fx + 1] + lbs[jj * 64 + fx + 1];
      float xln2 = d2 * invsd * lss[jj * 64 + fx + 2] + lbs[jj * 64 + fx + 2];
      float xln3 = d3 * invsd * lss[jj * 64 + fx + 3] + lbs[jj * 64 + fx + 3];
      float4 bp = *(const float4*)(bparam + ((long)(j0 + jj) * S_N + s) * 64 + fx);
      float a0 = bp.x, a1 = bp.y, a2 = bp.z, a3 = bp.w;
#pragma unroll
      for (int t16 = 0; t16 < 16; t16++) {
        int src = g0 + t16;
        float h0 = __shfl(xln0, src, 64);
        float h1 = __shfl(xln1, src, 64);
        float h2 = __shfl(xln2, src, 64);
        float h3 = __shfl(xln3, src, 64);
        const float* wrow = w2s + jj * 4096 + (t16 * 4) * 64 + fx;
        float4 w0 = *(const float4*)(wrow);
        float4 w1 = *(const float4*)(wrow + 64);
        float4 w2v = *(const float4*)(wrow + 128);
        float4 w3v = *(const float4*)(wrow + 192);
        a0 += h0 * w0.x + h1 * w1.x + h2 * w2v.x + h3 * w3v.x;
        a1 += h0 * w0.y + h1 * w1.y + h2 * w2v.y + h3 * w3v.y;
        a2 += h0 * w0.z + h1 * w1.z + h2 * w2v.z + h3 * w3v.z;
        a3 += h0 * w0.w + h1 * w1.w + h2 * w2v.w + h3 * w3v.w;
      }
      float4 o4 = {a0, a1, a2, a3};
      *(float4*)(xprime + (((long)(b * J_N + j0 + jj)) * S_N + s) * 64 + fx) = o4;
    }
  }
}

// ---- ktqt16: gated LN'd K/Q fragment production for unit blk in [0, NKT16) ----
__device__ void ktqt_body(int blk, float* smem, const float* __restrict__ esum_p,
                          const float* __restrict__ tau, const float* __restrict__ temp,
                          const float* __restrict__ proj,
                          _Float16* __restrict__ khi, _Float16* __restrict__ klo,
                          _Float16* __restrict__ qhi, _Float16* __restrict__ qlo) {
  _Float16* stg = (_Float16*)smem;        // [4][4096] halves = 32 KB
  int lane = threadIdx.x & 63;
  int bj = blk / 12, stile = blk - bj * 12;
  int b = bj >> 3, j = bj & 7;
  int w = threadIdx.x >> 6;
  int ig = lane >> 4;                     // i-group 0..3
  int f4 = (lane & 15) * 4;               // f base
  int iK = b * 8 + 2 * ig, iQ = iK + 1;
  float tv = fabsf(temp[0]) * SQRT_SF + 1e-4f;
  float gK = gate_g(esum_p, iK, j, tau, tv);
  float gQ = gate_g(esum_p, iQ, j, tau, tv);
  int slotbase = (lane >> 3) * 512 + ((lane >> 1) & 3) * 128 + (lane & 1) * 4;
  __syncthreads();
  for (int rr = 0; rr < 4; rr++) {
    int m16 = w * 4 + rr;
    int s = stile * 16 + m16;
    half4 hk4 = {}, lk4 = {}, hq4 = {}, lq4 = {};
    if (s < S_N) {
      float4 kr = *(const float4*)(proj + ((long)iK * S_N + s) * 64 + f4);
      float4 qr = *(const float4*)(proj + ((long)iQ * S_N + s) * 64 + f4);
      float kv[4] = {kr.x * gK, kr.y * gK, kr.z * gK, kr.w * gK};
      float qv[4] = {qr.x * gQ, qr.y * gQ, qr.z * gQ, qr.w * gQ};
      float mkv = wave_sum(kv[0] + kv[1] + kv[2] + kv[3]) * (1.f / 256.f);
      float mqv = wave_sum(qv[0] + qv[1] + qv[2] + qv[3]) * (1.f / 256.f);
      float vk = 0.f, vq = 0.f;
#pragma unroll
      for (int q = 0; q < 4; q++) {
        float dk = kv[q] - mkv; vk += dk * dk;
        float dq = qv[q] - mqv; vq += dq * dq;
      }
      vk = wave_sum(vk) * (1.f / 256.f);
      vq = wave_sum(vq) * (1.f / 256.f);
      float ik = 1.f / sqrtf(vk + 1e-5f);
      float iq = 1.f / sqrtf(vq + 1e-5f);
#pragma unroll
      for (int q = 0; q < 4; q++) {
        float fk = (kv[q] - mkv) * ik;
        float fq = (qv[q] - mqv) * iq;
        _Float16 hk = (_Float16)fk;
        _Float16 hq = (_Float16)fq;
        hk4[q] = hk; lk4[q] = (_Float16)(fk - (float)hk);
        hq4[q] = hq; lq4[q] = (_Float16)(fq - (float)hq);
      }
    }
    int off = slotbase + m16 * 8;
    *(half4*)&stg[0 * 4096 + off] = hk4;
    *(half4*)&stg[1 * 4096 + off] = lk4;
    *(half4*)&stg[2 * 4096 + off] = hq4;
    *(half4*)&stg[3 * 4096 + off] = lq4;
  }
  __syncthreads();
  long gb = ((long)bj * 12 + stile) * 4096;
  float4* dk = (float4*)(khi + gb);
  float4* dkl = (float4*)(klo + gb);
  float4* dq = (float4*)(qhi + gb);
  float4* dql = (float4*)(qlo + gb);
  const float4* s0 = (const float4*)(stg + 0 * 4096);
  const float4* s1 = (const float4*)(stg + 1 * 4096);
  const float4* s2 = (const float4*)(stg + 2 * 4096);
  const float4* s3 = (const float4*)(stg + 3 * 4096);
  int t = threadIdx.x;
  dk[t] = s0[t];  dk[t + 256] = s0[t + 256];
  dkl[t] = s1[t]; dkl[t + 256] = s1[t + 256];
  dq[t] = s2[t];  dq[t + 256] = s2[t + 256];
  dql[t] = s3[t]; dql[t + 256] = s3[t + 256];
}

// ---- rawfinal: MFMA scores -> softmax -> apply/conv/residual, unit bid ----
__device__ void rawfinal_body(int bid, float* smem,
                              const _Float16* __restrict__ khi, const _Float16* __restrict__ klo,
                              const _Float16* __restrict__ qhi, const _Float16* __restrict__ qlo,
                              const float* __restrict__ temp, const float* __restrict__ xprime,
                              const float* __restrict__ comb, const float* __restrict__ w3,
                              const float* __restrict__ alpha, const float* __restrict__ beta,
                              const float* __restrict__ theta, const float* __restrict__ gamma,
                              float* __restrict__ out) {
  float* w1t = smem;             // 16 * 196 = 3136
  float* w3s = smem + 3136;      // 16 * 64 = 1024, [k][o], tap 15 = 0
  int xcd = bid & 7;
  int idx = bid >> 3;            // 0..95
  int bj = xcd * 8 + idx / 12;
  int stile = idx - (idx / 12) * 12;
  int j = bj & 7;
  int w = threadIdx.x >> 6, lane = threadIdx.x & 63;
  int quad = lane >> 4, m16 = lane & 15;
  long fb = (long)bj * FRAG_BJ + lane * 8;
  __syncthreads();
  for (int t = threadIdx.x; t < 16 * 64; t += 256) {
    int k = t >> 6, o = t & 63;
    w3s[t] = (k < KS_N) ? w3[j * 64 * KS_N + o * KS_N + k] : 0.f;
  }
  for (int t = threadIdx.x; t < 16 * 9; t += 256) {
    int r = t / 9, c = 187 + (t - r * 9);
    w1t[r * W1STRIDE + c] = 0.f;
  }
  const _Float16* ah_p = khi + fb + (long)stile * 4096;
  const _Float16* al_p = klo + fb + (long)stile * 4096;
  floatx4 acc[3] = {};
  for (int ec = 0; ec < 8; ec++) {
    half8 ah = *(const half8*)(ah_p + ec * 512);
    half8 al = *(const half8*)(al_p + ec * 512);
#pragma unroll
    for (int n = 0; n < 3; n++) {
      long bo = fb + (long)(w * 3 + n) * 4096 + ec * 512;
      half8 bh = *(const half8*)(qhi + bo);
      half8 bl = *(const half8*)(qlo + bo);
      acc[n] = __builtin_amdgcn_mfma_f32_16x16x32_f16(ah, bh, acc[n], 0, 0, 0);
      acc[n] = __builtin_amdgcn_mfma_f32_16x16x32_f16(al, bh, acc[n], 0, 0, 0);
      acc[n] = __builtin_amdgcn_mfma_f32_16x16x32_f16(ah, bl, acc[n], 0, 0, 0);
    }
  }
  float tv = fabsf(temp[0]) * SQRT_SF + 1e-4f;
  float scale = 1.f / (16.f * tv);
#pragma unroll
  for (int n = 0; n < 3; n++) {
    int t = (w * 3 + n) * 16 + m16;  // 0..191
    if (t < S_N) {
#pragma unroll
      for (int r = 0; r < 4; r++)
        w1t[(quad * 4 + r) * W1STRIDE + t] = acc[n][r] * scale;
    }
  }
  __syncthreads();
  int o = lane;
#pragma unroll
  for (int rr = 0; rr < 4; rr++) {
    float* row = &w1t[(w * 4 + rr) * W1STRIDE];
    float v[3];
    float m = -1e30f;
#pragma unroll
    for (int q = 0; q < 3; q++) {
      int t = o + q * 64;
      v[q] = (t < S_N) ? row[t] : -1e30f;
      m = fmaxf(m, v[q]);
    }
    m = wave_max(m);
    float ssum = 0.f;
#pragma unroll
    for (int q = 0; q < 3; q++) {
      int t = o + q * 64;
      float e = (t < S_N) ? expf(v[q] - m) : 0.f;
      v[q] = e;
      ssum += e;
    }
    ssum = wave_sum(ssum);
    float invs = 1.f / ssum;
#pragma unroll
    for (int q = 0; q < 3; q++) {
      int t = o + q * 64;
      if (t < S_N) row[t] = v[q] * invs;
    }
  }
  __syncthreads();
  int h = lane >> 5, o2 = lane & 31;
  int o0 = o2 * 2;
  const float* xpg = xprime + (long)bj * (S_N * 64);
  float aa = fabsf(alpha[j]), ba = fabsf(beta[j]), ta = fabsf(theta[j]), gv = gamma[j];
  int s0 = stile * 16;
  int tbase = h * 96;
  float ax[4] = {0.f, 0.f, 0.f, 0.f}, ay[4] = {0.f, 0.f, 0.f, 0.f};
  for (int tb = 0; tb < 96; tb += 4) {
    float4 wv[4];
#pragma unroll
    for (int rr = 0; rr < 4; rr++)
      wv[rr] = *(const float4*)&w1t[(w * 4 + rr) * W1STRIDE + tbase + tb];
#pragma unroll
    for (int q = 0; q < 4; q++) {
      int t = tbase + tb + q;
      int tc = (t < S_N) ? t : S_N - 1;   // weight is 0 for t>=187
      float2 xv = *(const float2*)(xpg + tc * 64 + o0);
      float w0 = ((const float*)&wv[0])[q];
      float w1 = ((const float*)&wv[1])[q];
      float w2 = ((const float*)&wv[2])[q];
      float w3q = ((const float*)&wv[3])[q];
      ax[0] += w0 * xv.x; ay[0] += w0 * xv.y;
      ax[1] += w1 * xv.x; ay[1] += w1 * xv.y;
      ax[2] += w2 * xv.x; ay[2] += w2 * xv.y;
      ax[3] += w3q * xv.x; ay[3] += w3q * xv.y;
    }
  }
  float cx[4] = {0.f, 0.f, 0.f, 0.f}, cy[4] = {0.f, 0.f, 0.f, 0.f};
#pragma unroll
  for (int k = 0; k < 8; k++) {
    int kk = h * 8 + k;               // 0..15
    float2 wv3 = *(const float2*)&w3s[kk * 64 + o0];
#pragma unroll
    for (int rr = 0; rr < 4; rr++) {
      int si = s0 + w * 4 + rr + kk - 7;
      int sc = si < 0 ? 0 : (si >= S_N ? S_N - 1 : si);
      float2 xv = *(const float2*)(xpg + sc * 64 + o0);
      bool ok = (si >= 0) && (si < S_N);
      cx[rr] += ok ? wv3.x * xv.x : 0.f;
      cy[rr] += ok ? wv3.y * xv.y : 0.f;
    }
  }
#pragma unroll
  for (int rr = 0; rr < 4; rr++) {
    float px = ba * ax[rr] + ta * cx[rr];
    float py = ba * ay[rr] + ta * cy[rr];
    px += __shfl_xor(px, 32, 64);
    py += __shfl_xor(py, 32, 64);
    int s = s0 + w * 4 + rr;
    if (s < S_N) {
      float2 xs = *(const float2*)(xpg + s * 64 + o0);
      float2 cv = *(const float2*)(comb + ((long)bj * S_N + s) * 64 + o0);
      float2 res;
      res.x = px + aa * xs.x + gv * cv.x;
      res.y = py + aa * xs.y + gv * cv.y;
      if ((h == 0) == (rr < 2))   // h=0 writes rows 0,1; h=1 writes rows 2,3
        *(float2*)(out + ((long)bj * S_N + s) * 64 + o0) = res;
    }
  }
}

// ================= cooperative mega-kernel (1 launch, 3 grid syncs) =========
__global__ __launch_bounds__(256, 3) void k_mega(
    const float4* x4, const float* sw, const float* omiga, const float* tau,
    const float* temp, const float* proj, const float* W2, const float* bparam,
    const float* lns, const float* lnb, const float* w3, const float* alpha,
    const float* beta, const float* theta, const float* gamma,
    float* maxp, float* esum_p, float4* act4,
    _Float16* khi, _Float16* klo, _Float16* qhi, _Float16* qlo,
    float4* comb4, float* xprime, float* out) {
  __shared__ float smem[SMEM_F];
  cg::grid_group grid = cg::this_grid();
  int bid = blockIdx.x, tid = threadIdx.x;
  // ---- P0: maxabs partials (768 blocks, single pass over 3 MB) ----
  {
    const int n4 = (B_N * IN_N * S_N * F_N) / 4;
    float m = 0.f;
    int i = bid * 256 + tid;
    if (i < n4) {
      float4 v = x4[i];
      m = fmaxf(fmaxf(fabsf(v.x), fabsf(v.y)), fmaxf(fabsf(v.z), fabsf(v.w)));
    }
    m = wave_max(m);
    if ((tid & 63) == 0) smem[tid >> 6] = m;
    __syncthreads();
    if (tid == 0) maxp[bid] = fmaxf(fmaxf(smem[0], smem[1]), fmaxf(smem[2], smem[3]));
  }
  grid.sync();
  // ---- P1: spline (768 = 12 tiles x 64 planes, 1:1) ----
  float inv = inv_from_partials(maxp, NMEGA);
  spline_body(bid % 12, bid / 12, inv, smem, x4, sw, omiga, act4, esum_p);
  grid.sync();
  // ---- P2: mid2 (384 comb_xp || 384 x 2 ktqt units) ----
  if (bid < NCOMB) {
    comb_xp_body(bid, smem, act4, esum_p, tau, temp, W2, bparam, lns, lnb, comb4, xprime);
  } else {
    int base = (bid - NCOMB) * 2;
    ktqt_body(base, smem, esum_p, tau, temp, proj, khi, klo, qhi, qlo);
    ktqt_body(base + 1, smem, esum_p, tau, temp, proj, khi, klo, qhi, qlo);
  }
  grid.sync();
  // ---- P3: rawfinal (768, 1:1) ----
  rawfinal_body(bid, smem, khi, klo, qhi, qlo, temp, xprime,
                (const float*)comb4, w3, alpha, beta, theta, gamma, out);
}

// ================= fallback kernels (proven 4-launch path) ==================
__global__ void k_maxabs(const float4* __restrict__ x, float* __restrict__ maxp, int n4) {
  __shared__ float red[4];
  int tid = blockIdx.x * 256 + threadIdx.x;
  float m = 0.f;
  for (int i = tid; i < n4; i += gridDim.x * 256) {
    float4 v = x[i];
    m = fmaxf(m, fmaxf(fmaxf(fabsf(v.x), fabsf(v.y)), fmaxf(fabsf(v.z), fabsf(v.w))));
  }
  m = wave_max(m);
  if ((threadIdx.x & 63) == 0) red[threadIdx.x >> 6] = m;
  __syncthreads();
  if (threadIdx.x == 0)
    maxp[blockIdx.x] = fmaxf(fmaxf(red[0], red[1]), fmaxf(red[2], red[3]));
}
__global__ void k_spline(const float4* x4, const float* sw, const float* omiga,
                         const float* maxp, float4* act4, float* esum_p) {
  __shared__ float smem[576];
  float inv = inv_from_partials(maxp, NMAXP);
  spline_body(blockIdx.x, blockIdx.y, inv, smem, x4, sw, omiga, act4, esum_p);
}
__global__ void k_mid2(const float4* act4, const float* esum_p, const float* tau,
                       const float* temp, const float* proj, const float* W2,
                       const float* bparam, const float* lns, const float* lnb,
                       float4* comb4, float* xprime,
                       _Float16* khi, _Float16* klo, _Float16* qhi, _Float16* qlo) {
  __shared__ float smem[SMEM_F];
  if (blockIdx.x < NCOMB)
    comb_xp_body(blockIdx.x, smem, act4, esum_p, tau, temp, W2, bparam, lns, lnb,
                 comb4, xprime);
  else
    ktqt_body(blockIdx.x - NCOMB, smem, esum_p, tau, temp, proj, khi, klo, qhi, qlo);
}
__global__ void k_rawfinal(const _Float16* khi, const _Float16* klo, const _Float16* qhi,
                           const _Float16* qlo, const float* temp, const float* xprime,
                           const float* comb, const float* w3, const float* alpha,
                           const float* beta, const float* theta, const float* gamma,
                           float* out) {
  __shared__ float smem[4160];
  rawfinal_body(blockIdx.x, smem, khi, klo, qhi, qlo, temp, xprime, comb, w3,
                alpha, beta, theta, gamma, out);
}

extern "C" void kernel_launch(void* const* d_in, const int* in_sizes, int n_in,
                              void* d_out, int out_size, void* d_ws, size_t ws_size,
                              hipStream_t stream) {
  const float4* x4    = (const float4*)d_in[0];
  const float* proj   = (const float*)d_in[1];
  const float* sw     = (const float*)d_in[2];
  const float* tau    = (const float*)d_in[3];
  const float* temp   = (const float*)d_in[4];
  const float* omiga  = (const float*)d_in[5];
  const float* W2     = (const float*)d_in[6];
  const float* bparam = (const float*)d_in[7];
  const float* lns    = (const float*)d_in[8];
  const float* lnb    = (const float*)d_in[9];
  const float* alpha  = (const float*)d_in[10];
  const float* beta   = (const float*)d_in[11];
  const float* theta  = (const float*)d_in[12];
  const float* gamma  = (const float*)d_in[13];
  const float* w3     = (const float*)d_in[14];

  float* out = (float*)d_out;
  float* xprime = out + B_N * J_N * S_N * O_N;  // second output, written directly

  float* wsf = (float*)d_ws;
  float* maxp   = wsf;                            // 768 floats (mega) / 256 (fallback)
  float* esum_p = wsf + 768;                      // 512*12 floats
  float* act    = wsf + 768 + 512 * NT_SPL;       // 24.5 MB
  const long ACT_N = (long)64 * 8 * SF_N;
  const long FR = (long)64 * FRAG_BJ;             // 3,145,728 halves per frag array
  _Float16* khi = (_Float16*)(act + ACT_N);
  _Float16* klo = khi + FR;
  _Float16* qhi = klo + FR;
  _Float16* qlo = qhi + FR;
  float* comb = (float*)(qlo + FR);
  float4* act4 = (float4*)act;
  float4* comb4 = (float4*)comb;

  void* args[] = {&x4, &sw, &omiga, &tau, &temp, &proj, &W2, &bparam, &lns, &lnb,
                  &w3, &alpha, &beta, &theta, &gamma, &maxp, &esum_p, &act4,
                  &khi, &klo, &qhi, &qlo, &comb4, &xprime, &out};
  hipError_t err = hipLaunchCooperativeKernel((const void*)k_mega, dim3(NMEGA), dim3(256),
                                              args, 0, stream);
  if (err != hipSuccess) {
    (void)hipGetLastError();   // clear sticky error; use proven 4-launch path
    k_maxabs<<<NMAXP, 256, 0, stream>>>(x4, maxp, (B_N * IN_N * S_N * F_N) / 4);
    k_spline<<<dim3(NT_SPL, 64), 256, 0, stream>>>(x4, sw, omiga, maxp, act4, esum_p);
    k_mid2<<<NCOMB + NKT16, 256, 0, stream>>>(act4, esum_p, tau, temp, proj, W2,
                                              bparam, lns, lnb, comb4, xprime,
                                              khi, klo, qhi, qlo);
    k_rawfinal<<<NRF, 256, 0, stream>>>(khi, klo, qhi, qlo, temp, xprime, comb,
                                        w3, alpha, beta, theta, gamma, out);
  }
}

// Round 11
// 142.612 us; speedup vs baseline: 2.9581x; 2.9581x over previous
//
#include <hip/hip_runtime.h>
#include <math.h>

#define B_N 8
#define IN_N 8
#define J_N 8
#define S_N 187
#define F_N 64
#define O_N 64
#define C_N 67
#define KS_N 15
#define SF_N (S_N * F_N)   // 11968
#define SF4_N (SF_N / 4)   // 2992 float4s per (b,i) plane
#define SQRT_SF 0.85467470f  // sqrt(187/256)

#define NT_SPL 12           // 1024-wide idx tiles (256 float4/block) covering SF_N
#define NCOMB 384           // combined+xp blocks (8 b * 4 jg * 12 tiles)
#define NKT16 768           // ktqt16 blocks (64 bj * 12 stiles)
#define NRF 768             // rawfinal blocks (64 bj * 12 stiles)
#define NMAXP 256           // maxabs partial blocks
#define FRAG_BJ 49152       // 12 stiles * 4096 halves per bj
#define W1STRIDE 196        // w1t row stride: 16B-aligned, bank-staggered

typedef __attribute__((ext_vector_type(8))) _Float16 half8;
typedef __attribute__((ext_vector_type(4))) _Float16 half4;
typedef __attribute__((ext_vector_type(4))) float floatx4;

// ---------------- wave helpers (wave = 64) ----------------
__device__ __forceinline__ float wave_sum(float v) {
#pragma unroll
  for (int off = 32; off > 0; off >>= 1) v += __shfl_down(v, off, 64);
  return __shfl(v, 0, 64);
}
__device__ __forceinline__ float wave_max(float v) {
#pragma unroll
  for (int off = 32; off > 0; off >>= 1) v = fmaxf(v, __shfl_down(v, off, 64));
  return __shfl(v, 0, 64);
}
__device__ __forceinline__ float bspline(float d) {
  float t2 = fmaxf(2.f - d, 0.f);
  float t1 = fmaxf(1.f - d, 0.f);
  return t2 * t2 * t2 * (1.f / 6.f) - t1 * t1 * t1 * (4.f / 6.f);
}
__device__ __forceinline__ float get_inv095(const float* __restrict__ maxp) {
  int lane = threadIdx.x & 63;
  float m = 0.f;
#pragma unroll
  for (int k = 0; k < NMAXP / 64; k++) m = fmaxf(m, maxp[lane + k * 64]);
  return 0.95f / (wave_max(m) + 1e-8f);
}
// gate = (sqrtE/tau) * sigmoid((sqrtE-tau)/tv) from the 12 per-tile partials
__device__ __forceinline__ float gate_g(const float* __restrict__ esum_p, int bi, int j,
                                        const float* __restrict__ tau, float tv) {
  const float* p = esum_p + ((long)bi * 8 + j) * NT_SPL;
  float s = 0.f;
#pragma unroll
  for (int k = 0; k < NT_SPL; k++) s += p[k];
  float sE = sqrtf(s * (1.f / (float)SF_N) + 1e-8f);
  float ta = fabsf(tau[(bi & 7) * 8 + j]);
  return (sE / (ta + 1e-8f)) / (1.f + expf(-(sE - ta) / tv));
}
// LDS staging swizzle (involution on float4-granule index): spreads the
// fragment scatter-writes from 2 banks (32-way conflict, 2.16M extra LDS
// cycles measured in R10's mega profile) to 16 bank-pairs (4-way, the
// optimal for 8B stores). Applied at write AND read -> global layout
// byte-identical.
__device__ __forceinline__ int swz_u(int u) { return u ^ ((u >> 4) & 7); }

// ---------------- D1. global max |x| -> per-block maxima ----------------
__global__ void k_maxabs(const float4* __restrict__ x, float* __restrict__ maxp, int n4) {
  __shared__ float red[4];
  int tid = blockIdx.x * 256 + threadIdx.x;
  float m = 0.f;
  for (int i = tid; i < n4; i += gridDim.x * 256) {
    float4 v = x[i];
    m = fmaxf(m, fmaxf(fmaxf(fabsf(v.x), fabsf(v.y)), fmaxf(fabsf(v.z), fabsf(v.w))));
  }
  m = wave_max(m);
  if ((threadIdx.x & 63) == 0) red[threadIdx.x >> 6] = m;
  __syncthreads();
  if (threadIdx.x == 0)
    maxp[blockIdx.x] = fmaxf(fmaxf(red[0], red[1]), fmaxf(red[2], red[3]));
}

// ---------------- D2. spline ONCE (float4-vectorized): act + energies ---
// Weight rows at stride 12 floats (48B, 16B-aligned): b128 bank-starts
// cycle 8 positions (12c mod 32) instead of 4 (8c mod 32) -> 16-way
// conflicts drop to the b128-inherent 8-way floor.
__global__ void k_spline(const float4* __restrict__ x4, const float* __restrict__ sw,
                         const float* __restrict__ omiga, const float* __restrict__ maxp,
                         float4* __restrict__ act4, float* __restrict__ esum_p) {
  int tile = blockIdx.x, bi = blockIdx.y;
  int i = bi & 7;
  __shared__ float wl[C_N * 12];  // [c][j] rows, stride 12
  __shared__ float aom[J_N];
  __shared__ float red[4 * J_N];
  for (int t = threadIdx.x; t < J_N * C_N; t += 256) {
    int j = t / C_N, c = t - j * C_N;
    wl[c * 12 + j] = sw[i * J_N * C_N + t];
  }
  if (threadIdx.x < J_N) aom[threadIdx.x] = fabsf(omiga[i * J_N + threadIdx.x]);
  int lane = threadIdx.x & 63, wid = threadIdx.x >> 6;
  float inv = get_inv095(maxp);
  __syncthreads();
  int i4 = tile * 256 + threadIdx.x;
  float e[J_N] = {0, 0, 0, 0, 0, 0, 0, 0};
  if (i4 < SF4_N) {
    float4 xv = x4[(long)bi * SF4_N + i4];
    float xs[4] = {xv.x, xv.y, xv.z, xv.w};
    float4 av[J_N];
#pragma unroll
    for (int c = 0; c < 4; c++) {
      float x = xs[c];
      float xn = fminf(fmaxf(x * inv, -0.99f), 0.99f);
      float u = (xn + 1.f) * 33.f;
      int c0 = (int)floorf(u) - 1;
      float sm[J_N] = {0, 0, 0, 0, 0, 0, 0, 0};
#pragma unroll
      for (int kk = 0; kk < 4; kk++) {
        int cc = c0 + kk;
        if (cc >= 0 && cc < C_N) {
          float bas = bspline(fabsf(u - (float)cc));
          const float4* wp = (const float4*)(wl + cc * 12);
          float4 wa = wp[0], wb = wp[1];
          sm[0] += bas * wa.x; sm[1] += bas * wa.y;
          sm[2] += bas * wa.z; sm[3] += bas * wa.w;
          sm[4] += bas * wb.x; sm[5] += bas * wb.y;
          sm[6] += bas * wb.z; sm[7] += bas * wb.w;
        }
      }
#pragma unroll
      for (int j = 0; j < J_N; j++) {
        float a = sm[j] + aom[j] * x;
        (&av[j].x)[c] = a;
        e[j] += a * a;
      }
    }
#pragma unroll
    for (int j = 0; j < J_N; j++) act4[((long)(bi * 8 + j)) * SF4_N + i4] = av[j];
  }
#pragma unroll
  for (int j = 0; j < J_N; j++) {
    float v = e[j];
#pragma unroll
    for (int off = 32; off > 0; off >>= 1) v += __shfl_down(v, off, 64);
    if (lane == 0) red[wid * J_N + j] = v;
  }
  __syncthreads();
  if (threadIdx.x < J_N)
    esum_p[((long)bi * 8 + threadIdx.x) * NT_SPL + tile] =
        red[threadIdx.x] + red[8 + threadIdx.x] + red[16 + threadIdx.x] + red[24 + threadIdx.x];
}

// ---------------- D3. mid2 = (combined+xp fused) U ktqt16 ---------------
__global__ void k_mid2(const float4* __restrict__ act4, const float* __restrict__ esum_p,
                       const float* __restrict__ tau, const float* __restrict__ temp,
                       const float* __restrict__ proj, const float* __restrict__ W2,
                       const float* __restrict__ bparam, const float* __restrict__ lns,
                       const float* __restrict__ lnb, float4* __restrict__ comb4,
                       float* __restrict__ xprime,
                       _Float16* __restrict__ khi, _Float16* __restrict__ klo,
                       _Float16* __restrict__ qhi, _Float16* __restrict__ qlo) {
  __shared__ float smem[8192 + 16 + 256];  // 33.9 KB: W2(2j) | mk | lss | lbs ; aliased by stg
  int lane = threadIdx.x & 63;
  if (blockIdx.x < NCOMB) {
    // ---- combined+xp: blk = (b*4 + jg)*12 + tile; j in {jg*2, jg*2+1} ----
    int blk = blockIdx.x;
    int tile = blk % 12, bjg = blk / 12;
    int jg = bjg & 3, b = bjg >> 2;
    int j0 = jg * 2;
    float* w2s = smem;             // [2][64][64]
    float* mk  = smem + 8192;      // 16
    float* lss = smem + 8208;      // [2][64]
    float* lbs = smem + 8336;      // [2][64]
    {
      const float4* wg = (const float4*)(W2 + j0 * 4096);
      float4* ws4 = (float4*)w2s;
      for (int t = threadIdx.x; t < 2048; t += 256) ws4[t] = wg[t];
    }
    if (threadIdx.x < 128) {
      int jj = threadIdx.x >> 6, f = threadIdx.x & 63;
      lss[threadIdx.x] = lns[(j0 + jj) * 64 + f];
      lbs[threadIdx.x] = lnb[(j0 + jj) * 64 + f];
    }
    if (threadIdx.x < 16) {
      int i = threadIdx.x >> 1, j = j0 + (threadIdx.x & 1);
      const float* p = esum_p + ((long)(b * 8 + i) * 8 + j) * NT_SPL;
      float s = 0.f;
#pragma unroll
      for (int k = 0; k < NT_SPL; k++) s += p[k];
      float sE = sqrtf(s * (1.f / (float)SF_N) + 1e-8f);
      float ta = fabsf(tau[i * 8 + j]);
      float tv = fabsf(temp[0]) * SQRT_SF + 1e-4f;
      mk[threadIdx.x] = 1.f / (1.f + expf(-(sE - ta) / tv));
    }
    __syncthreads();
    int i4 = tile * 256 + threadIdx.x;
    if (i4 < SF4_N) {
      float4 cb[2] = {};
#pragma unroll
      for (int i = 0; i < IN_N; i++) {
#pragma unroll
        for (int jj = 0; jj < 2; jj++) {
          float4 a = act4[((long)((b * 8 + i) * 8 + j0 + jj)) * SF4_N + i4];
          float g = mk[i * 2 + jj];
          cb[jj].x += g * a.x; cb[jj].y += g * a.y;
          cb[jj].z += g * a.z; cb[jj].w += g * a.w;
        }
      }
#pragma unroll
      for (int jj = 0; jj < 2; jj++)
        comb4[((long)(b * J_N + j0 + jj)) * SF4_N + i4] = cb[jj];
      // ---- fused xp: LN over f (16-lane row) + W2 matmul + bparam ----
      int s = i4 >> 4;                       // global seq row (< S_N by guard)
      int fx = (threadIdx.x & 15) * 4;       // this lane's 4 o/h positions
      int g0 = lane & 48;                    // 16-lane group base within wave
#pragma unroll
      for (int jj = 0; jj < 2; jj++) {
        float4 c = cb[jj];
        float ls = c.x + c.y + c.z + c.w;
#pragma unroll
        for (int m = 1; m <= 8; m <<= 1) ls += __shfl_xor(ls, m, 64);
        float mean = ls * (1.f / 64.f);
        float d0 = c.x - mean, d1 = c.y - mean, d2 = c.z - mean, d3 = c.w - mean;
        float lv = d0 * d0 + d1 * d1 + d2 * d2 + d3 * d3;
#pragma unroll
        for (int m = 1; m <= 8; m <<= 1) lv += __shfl_xor(lv, m, 64);
        float invsd = 1.f / sqrtf(lv * (1.f / 64.f) + 1e-5f);
        float xln0 = d0 * invsd * lss[jj * 64 + fx + 0] + lbs[jj * 64 + fx + 0];
        float xln1 = d1 * invsd * lss[jj * 64 + fx + 1] + lbs[jj * 64 + fx + 1];
        float xln2 = d2 * invsd * lss[jj * 64 + fx + 2] + lbs[jj * 64 + fx + 2];
        float xln3 = d3 * invsd * lss[jj * 64 + fx + 3] + lbs[jj * 64 + fx + 3];
        float4 bp = *(const float4*)(bparam + ((long)(j0 + jj) * S_N + s) * 64 + fx);
        float a0 = bp.x, a1 = bp.y, a2 = bp.z, a3 = bp.w;
#pragma unroll
        for (int t16 = 0; t16 < 16; t16++) {
          int src = g0 + t16;
          float h0 = __shfl(xln0, src, 64);
          float h1 = __shfl(xln1, src, 64);
          float h2 = __shfl(xln2, src, 64);
          float h3 = __shfl(xln3, src, 64);
          const float* wrow = w2s + jj * 4096 + (t16 * 4) * 64 + fx;
          float4 w0 = *(const float4*)(wrow);
          float4 w1 = *(const float4*)(wrow + 64);
          float4 w2v = *(const float4*)(wrow + 128);
          float4 w3v = *(const float4*)(wrow + 192);
          a0 += h0 * w0.x + h1 * w1.x + h2 * w2v.x + h3 * w3v.x;
          a1 += h0 * w0.y + h1 * w1.y + h2 * w2v.y + h3 * w3v.y;
          a2 += h0 * w0.z + h1 * w1.z + h2 * w2v.z + h3 * w3v.z;
          a3 += h0 * w0.w + h1 * w1.w + h2 * w2v.w + h3 * w3v.w;
        }
        float4 o4 = {a0, a1, a2, a3};
        *(float4*)(xprime + (((long)(b * J_N + j0 + jj)) * S_N + s) * 64 + fx) = o4;
      }
    }
  } else {
    // ---- ktqt16: block = (bj, stile); wave w rows stile*16 + w*4 .. +3 ----
    // stg addressed by swizzled float4-granule: write conflicts 32-way -> 4-way.
    _Float16* stg = (_Float16*)smem;        // [4][4096] halves = 32 KB
    int blk = blockIdx.x - NCOMB;           // 0..767
    int bj = blk / 12, stile = blk - bj * 12;
    int b = bj >> 3, j = bj & 7;
    int w = threadIdx.x >> 6;
    int ig = lane >> 4;                     // i-group 0..3
    int f4 = (lane & 15) * 4;               // f base
    int iK = b * 8 + 2 * ig, iQ = iK + 1;
    float tv = fabsf(temp[0]) * SQRT_SF + 1e-4f;
    float gK = gate_g(esum_p, iK, j, tau, tv);
    float gQ = gate_g(esum_p, iQ, j, tau, tv);
    int ubase = (lane >> 3) * 64 + ((lane >> 1) & 3) * 16;  // float4-granule base
    int intra = (lane & 1) * 4;                             // halves within granule
    for (int rr = 0; rr < 4; rr++) {
      int m16 = w * 4 + rr;
      int s = stile * 16 + m16;
      half4 hk4 = {}, lk4 = {}, hq4 = {}, lq4 = {};
      if (s < S_N) {
        float4 kr = *(const float4*)(proj + ((long)iK * S_N + s) * 64 + f4);
        float4 qr = *(const float4*)(proj + ((long)iQ * S_N + s) * 64 + f4);
        float kv[4] = {kr.x * gK, kr.y * gK, kr.z * gK, kr.w * gK};
        float qv[4] = {qr.x * gQ, qr.y * gQ, qr.z * gQ, qr.w * gQ};
        float mkv = wave_sum(kv[0] + kv[1] + kv[2] + kv[3]) * (1.f / 256.f);
        float mqv = wave_sum(qv[0] + qv[1] + qv[2] + qv[3]) * (1.f / 256.f);
        float vk = 0.f, vq = 0.f;
#pragma unroll
        for (int q = 0; q < 4; q++) {
          float dk = kv[q] - mkv; vk += dk * dk;
          float dq = qv[q] - mqv; vq += dq * dq;
        }
        vk = wave_sum(vk) * (1.f / 256.f);
        vq = wave_sum(vq) * (1.f / 256.f);
        float ik = 1.f / sqrtf(vk + 1e-5f);
        float iq = 1.f / sqrtf(vq + 1e-5f);
#pragma unroll
        for (int q = 0; q < 4; q++) {
          float fk = (kv[q] - mkv) * ik;
          float fq = (qv[q] - mqv) * iq;
          _Float16 hk = (_Float16)fk;
          _Float16 hq = (_Float16)fq;
          hk4[q] = hk; lk4[q] = (_Float16)(fk - (float)hk);
          hq4[q] = hq; lq4[q] = (_Float16)(fq - (float)hq);
        }
      }
      int off = swz_u(ubase + m16) * 8 + intra;
      *(half4*)&stg[0 * 4096 + off] = hk4;
      *(half4*)&stg[1 * 4096 + off] = lk4;
      *(half4*)&stg[2 * 4096 + off] = hq4;
      *(half4*)&stg[3 * 4096 + off] = lq4;
    }
    __syncthreads();
    // streamed write-out: logical granule t lives at physical swz_u(t)
    long gb = ((long)bj * 12 + stile) * 4096;
    float4* dk = (float4*)(khi + gb);
    float4* dkl = (float4*)(klo + gb);
    float4* dq = (float4*)(qhi + gb);
    float4* dql = (float4*)(qlo + gb);
    const float4* s0 = (const float4*)(stg + 0 * 4096);
    const float4* s1 = (const float4*)(stg + 1 * 4096);
    const float4* s2 = (const float4*)(stg + 2 * 4096);
    const float4* s3 = (const float4*)(stg + 3 * 4096);
    int t = threadIdx.x;
    int t0 = swz_u(t), t1 = swz_u(t + 256);
    dk[t] = s0[t0];  dk[t + 256] = s0[t1];
    dkl[t] = s1[t0]; dkl[t + 256] = s1[t1];
    dq[t] = s2[t0];  dq[t + 256] = s2[t1];
    dql[t] = s3[t0]; dql[t + 256] = s3[t1];
  }
}

// ---------------- D4. rawfinal768: MFMA -> LDS scores -> softmax -> apply
__global__ void k_rawfinal(const _Float16* __restrict__ khi, const _Float16* __restrict__ klo,
                           const _Float16* __restrict__ qhi, const _Float16* __restrict__ qlo,
                           const float* __restrict__ temp, const float* __restrict__ xprime,
                           const float* __restrict__ comb, const float* __restrict__ w3,
                           const float* __restrict__ alpha, const float* __restrict__ beta,
                           const float* __restrict__ theta, const float* __restrict__ gamma,
                           float* __restrict__ out) {
  __shared__ float w1t[16 * W1STRIDE];   // 12544 B
  __shared__ float w3s[16 * 64];         // 4096 B, [k][o], tap 15 = 0
  int xcd = blockIdx.x & 7;
  int idx = blockIdx.x >> 3;        // 0..95
  int bj = xcd * 8 + idx / 12;
  int stile = idx - (idx / 12) * 12;
  int j = bj & 7;
  int w = threadIdx.x >> 6, lane = threadIdx.x & 63;
  int quad = lane >> 4, m16 = lane & 15;
  long fb = (long)bj * FRAG_BJ + lane * 8;
  // stage w3 transposed [k][o]; tap 15 zeroed
  for (int t = threadIdx.x; t < 16 * 64; t += 256) {
    int k = t >> 6, o = t & 63;
    w3s[t] = (k < KS_N) ? w3[j * 64 * KS_N + o * KS_N + k] : 0.f;
  }
  // zero w1t tail cols 187..195 (survive MFMA store: it guards t < S_N)
  for (int t = threadIdx.x; t < 16 * 9; t += 256) {
    int r = t / 9, c = 187 + (t - r * 9);
    w1t[r * W1STRIDE + c] = 0.f;
  }
  // ---- MFMA: A = this stile's 16 rows; wave w computes tt = 3w..3w+2 ----
  const _Float16* ah_p = khi + fb + (long)stile * 4096;
  const _Float16* al_p = klo + fb + (long)stile * 4096;
  floatx4 acc[3] = {};
  for (int ec = 0; ec < 8; ec++) {
    half8 ah = *(const half8*)(ah_p + ec * 512);
    half8 al = *(const half8*)(al_p + ec * 512);
#pragma unroll
    for (int n = 0; n < 3; n++) {
      long bo = fb + (long)(w * 3 + n) * 4096 + ec * 512;
      half8 bh = *(const half8*)(qhi + bo);
      half8 bl = *(const half8*)(qlo + bo);
      acc[n] = __builtin_amdgcn_mfma_f32_16x16x32_f16(ah, bh, acc[n], 0, 0, 0);
      acc[n] = __builtin_amdgcn_mfma_f32_16x16x32_f16(al, bh, acc[n], 0, 0, 0);
      acc[n] = __builtin_amdgcn_mfma_f32_16x16x32_f16(ah, bl, acc[n], 0, 0, 0);
    }
  }
  float tv = fabsf(temp[0]) * SQRT_SF + 1e-4f;
  float scale = 1.f / (16.f * tv);
#pragma unroll
  for (int n = 0; n < 3; n++) {
    int t = (w * 3 + n) * 16 + m16;  // 0..191
    if (t < S_N) {
#pragma unroll
      for (int r = 0; r < 4; r++)
        w1t[(quad * 4 + r) * W1STRIDE + t] = acc[n][r] * scale;
    }
  }
  __syncthreads();
  // ---- softmax on this wave's 4 rows ----
  int o = lane;
#pragma unroll
  for (int rr = 0; rr < 4; rr++) {
    float* row = &w1t[(w * 4 + rr) * W1STRIDE];
    float v[3];
    float m = -1e30f;
#pragma unroll
    for (int q = 0; q < 3; q++) {
      int t = o + q * 64;
      v[q] = (t < S_N) ? row[t] : -1e30f;
      m = fmaxf(m, v[q]);
    }
    m = wave_max(m);
    float ssum = 0.f;
#pragma unroll
    for (int q = 0; q < 3; q++) {
      int t = o + q * 64;
      float e = (t < S_N) ? expf(v[q] - m) : 0.f;
      v[q] = e;
      ssum += e;
    }
    ssum = wave_sum(ssum);
    float invs = 1.f / ssum;
#pragma unroll
    for (int q = 0; q < 3; q++) {
      int t = o + q * 64;
      if (t < S_N) row[t] = v[q] * invs;
    }
  }
  __syncthreads();
  // ---- apply + conv + residuals: float2 per lane, half-wave t-split ----
  int h = lane >> 5, o2 = lane & 31;
  int o0 = o2 * 2;
  const float* xpg = xprime + (long)bj * (S_N * 64);
  float aa = fabsf(alpha[j]), ba = fabsf(beta[j]), ta = fabsf(theta[j]), gv = gamma[j];
  int s0 = stile * 16;
  int tbase = h * 96;               // h=0: t in [0,96), h=1: [96,192) (cols >=187 are 0)
  float ax[4] = {0.f, 0.f, 0.f, 0.f}, ay[4] = {0.f, 0.f, 0.f, 0.f};
  for (int tb = 0; tb < 96; tb += 4) {
    float4 wv[4];
#pragma unroll
    for (int rr = 0; rr < 4; rr++)
      wv[rr] = *(const float4*)&w1t[(w * 4 + rr) * W1STRIDE + tbase + tb];
#pragma unroll
    for (int q = 0; q < 4; q++) {
      int t = tbase + tb + q;
      int tc = (t < S_N) ? t : S_N - 1;   // weight is 0 for t>=187
      float2 xv = *(const float2*)(xpg + tc * 64 + o0);
      float w0 = ((const float*)&wv[0])[q];
      float w1 = ((const float*)&wv[1])[q];
      float w2 = ((const float*)&wv[2])[q];
      float w3q = ((const float*)&wv[3])[q];
      ax[0] += w0 * xv.x; ay[0] += w0 * xv.y;
      ax[1] += w1 * xv.x; ay[1] += w1 * xv.y;
      ax[2] += w2 * xv.x; ay[2] += w2 * xv.y;
      ax[3] += w3q * xv.x; ay[3] += w3q * xv.y;
    }
  }
  // conv: taps split 8/8 across halves (tap 15 weight = 0)
  float cx[4] = {0.f, 0.f, 0.f, 0.f}, cy[4] = {0.f, 0.f, 0.f, 0.f};
#pragma unroll
  for (int k = 0; k < 8; k++) {
    int kk = h * 8 + k;               // 0..15
    float2 wv3 = *(const float2*)&w3s[kk * 64 + o0];
#pragma unroll
    for (int rr = 0; rr < 4; rr++) {
      int si = s0 + w * 4 + rr + kk - 7;
      int sc = si < 0 ? 0 : (si >= S_N ? S_N - 1 : si);
      float2 xv = *(const float2*)(xpg + sc * 64 + o0);
      bool ok = (si >= 0) && (si < S_N);
      cx[rr] += ok ? wv3.x * xv.x : 0.f;
      cy[rr] += ok ? wv3.y * xv.y : 0.f;
    }
  }
#pragma unroll
  for (int rr = 0; rr < 4; rr++) {
    float px = ba * ax[rr] + ta * cx[rr];
    float py = ba * ay[rr] + ta * cy[rr];
    px += __shfl_xor(px, 32, 64);
    py += __shfl_xor(py, 32, 64);
    int s = s0 + w * 4 + rr;
    if (s < S_N) {
      float2 xs = *(const float2*)(xpg + s * 64 + o0);
      float2 cv = *(const float2*)(comb + ((long)bj * S_N + s) * 64 + o0);
      float2 res;
      res.x = px + aa * xs.x + gv * cv.x;
      res.y = py + aa * xs.y + gv * cv.y;
      if ((h == 0) == (rr < 2))   // h=0 writes rows 0,1; h=1 writes rows 2,3
        *(float2*)(out + ((long)bj * S_N + s) * 64 + o0) = res;
    }
  }
}

extern "C" void kernel_launch(void* const* d_in, const int* in_sizes, int n_in,
                              void* d_out, int out_size, void* d_ws, size_t ws_size,
                              hipStream_t stream) {
  const float* x_in   = (const float*)d_in[0];
  const float* proj   = (const float*)d_in[1];
  const float* sw     = (const float*)d_in[2];
  const float* tau    = (const float*)d_in[3];
  const float* temp   = (const float*)d_in[4];
  const float* omiga  = (const float*)d_in[5];
  const float* W2     = (const float*)d_in[6];
  const float* bparam = (const float*)d_in[7];
  const float* lns    = (const float*)d_in[8];
  const float* lnb    = (const float*)d_in[9];
  const float* alpha  = (const float*)d_in[10];
  const float* beta   = (const float*)d_in[11];
  const float* theta  = (const float*)d_in[12];
  const float* gamma  = (const float*)d_in[13];
  const float* w3     = (const float*)d_in[14];

  float* out = (float*)d_out;
  float* xprime = out + B_N * J_N * S_N * O_N;  // second output, written directly

  float* wsf = (float*)d_ws;
  float* maxp   = wsf;                            // 256 floats
  float* esum_p = wsf + 512;                      // 512*12 floats
  float* act    = wsf + 512 + 512 * NT_SPL;       // 64*8*SF_N floats = 24.5 MB
  const long ACT_N = (long)64 * 8 * SF_N;
  const long FR = (long)64 * FRAG_BJ;             // 3,145,728 halves per frag array
  _Float16* khi = (_Float16*)(act + ACT_N);
  _Float16* klo = khi + FR;
  _Float16* qhi = klo + FR;
  _Float16* qlo = qhi + FR;
  float* comb = (float*)(qlo + FR);

  k_maxabs<<<NMAXP, 256, 0, stream>>>((const float4*)x_in, maxp, (B_N * IN_N * S_N * F_N) / 4);
  k_spline<<<dim3(NT_SPL, 64), 256, 0, stream>>>((const float4*)x_in, sw, omiga, maxp,
                                                 (float4*)act, esum_p);
  k_mid2<<<NCOMB + NKT16, 256, 0, stream>>>((const float4*)act, esum_p, tau, temp, proj,
                                            W2, bparam, lns, lnb, (float4*)comb, xprime,
                                            khi, klo, qhi, qlo);
  k_rawfinal<<<NRF, 256, 0, stream>>>(khi, klo, qhi, qlo, temp, xprime, comb,
                                      w3, alpha, beta, theta, gamma, out);
}